// Round 13
// baseline (412.379 us; speedup 1.0000x reference)
//
#include <hip/hip_runtime.h>
#include <hip/hip_bf16.h>
#include <stdint.h>

#define B_ROWS 16384
#define K_DIM  2048   // IN + H
#define H_DIM  1024
#define N_DIM  4096   // 4*H
#define KB     (K_DIM * 2)      // bytes per packed row (4096)
#define NT     (K_DIM / 64)     // 32 K-tiles of BK=64
#define BUF0   0u
#define BUF1   32768u           // LDS double buffer: A 16K + B 16K each

using f32x4  = __attribute__((ext_vector_type(4))) float;
using bf16x8 = __attribute__((ext_vector_type(8))) __bf16;

// RNE float -> bf16 (inputs are finite)
__device__ __forceinline__ unsigned short f2bf(float f) {
    union { float f; unsigned u; } v; v.f = f;
    unsigned r = v.u + 0x7fffu + ((v.u >> 16) & 1u);
    return (unsigned short)(r >> 16);
}

// async global->LDS, 16B/lane. LDS dest must be wave-uniform (HW adds lane*16).
__device__ __forceinline__ void gload16(const void* g, const void* l) {
    __builtin_amdgcn_global_load_lds(
        (const __attribute__((address_space(1))) void*)g,
        (__attribute__((address_space(3))) void*)l,
        16, 0, 0);
}

__device__ __forceinline__ float rcp1p(float e) {   // 1/(1+e)
    return __builtin_amdgcn_rcpf(1.f + e);
}

// ---------------- pack kernels (unchanged, verified) ----------------
__global__ void pack_a_kernel(const float* __restrict__ x, const float* __restrict__ h0,
                              unsigned short* __restrict__ A) {
    int tid = blockIdx.x * 256 + threadIdx.x;
    int64_t idx = (int64_t)tid * 4;
    int b = (int)(idx >> 11);
    int k = (int)(idx & 2047);
    const float* src = (k < 1024) ? (x + (int64_t)b * 1024 + k)
                                  : (h0 + (int64_t)b * 1024 + (k - 1024));
    float4 v = *(const float4*)src;
    ushort4 o;
    o.x = f2bf(v.x); o.y = f2bf(v.y); o.z = f2bf(v.z); o.w = f2bf(v.w);
    *(ushort4*)(A + idx) = o;
}

__global__ void pack_w_kernel(const float* __restrict__ wi, const float* __restrict__ wh,
                              const float* __restrict__ bi, const float* __restrict__ bh,
                              unsigned short* __restrict__ W, float* __restrict__ bias) {
    int tid = blockIdx.x * 256 + threadIdx.x;
    int64_t idx = (int64_t)tid * 4;
    int r = (int)(idx >> 11);
    int k = (int)(idx & 2047);
    int h = r >> 2, g = r & 3;
    const float* src = (k < 1024)
        ? (wi + (int64_t)g * 1048576 + (int64_t)h * 1024 + k)
        : (wh + (int64_t)g * 1048576 + (int64_t)h * 1024 + (k - 1024));
    float4 v = *(const float4*)src;
    ushort4 o;
    o.x = f2bf(v.x); o.y = f2bf(v.y); o.z = f2bf(v.z); o.w = f2bf(v.w);
    *(ushort4*)(W + idx) = o;
    if (k == 0) bias[r] = bi[g * 1024 + h] + bh[g * 1024 + h];
}

// ---- 128x128 GEMM, 2 BLOCKS/CU (cross-block overlap) + fused LSTM epilogue ----
// LDS buffer (x2 @ 0/32768): A kk0 @0 (8K), A kk1 @8192, B kk0 @16384, B kk1 @24576.
// 64 KiB total -> 2 blocks resident per CU: while one block's waves drain a
// barrier/waitcnt, the sibling block's waves feed the MFMA+LDS pipes (m114
// wave-level overlap -- the mechanism 1-block/CU 256^2 designs forbid).
// Swizzle/staging/read formulas: verified r2/r5 machinery at halved geometry.
//   subtile byte = (row&15)*64 + (col ^ ((row&8)<<2)); linear-dest gload_lds with
//   inverse-swizzled source (4 waves x 2 gloads per 8K kk-half chunk).
// Phase (2/K-tile) = { 8 ds_reads(this kk); 4 gloads(kk of t+1); BAR; lgkm0;
//   SCHED0 (rule 18); setprio1; 16 MFMA; setprio0; vmcnt(4); BAR }.
// Covering: vmcnt(4) each phase end drains the kk-half staged one phase earlier,
// which is read one phase later (after a BAR all waves pass post-wait). WAR:
// stage into NXT.kk hits a region last read >=2 barriers earlier (reads retired
// by that phase's all-wave lgkm0 before its BAR).

#define FENCE   asm volatile("" ::: "memory")
#define BAR     __builtin_amdgcn_s_barrier()
#define SCHED0  __builtin_amdgcn_sched_barrier(0)

#define PH_PRE  do { FENCE; BAR; \
                     asm volatile("s_waitcnt lgkmcnt(0)" ::: "memory"); \
                     SCHED0; __builtin_amdgcn_s_setprio(1); } while (0)
#define PH_POST_V do { __builtin_amdgcn_s_setprio(0); SCHED0; \
                       asm volatile("s_waitcnt vmcnt(4)" ::: "memory"); \
                       SCHED0; FENCE; BAR; } while (0)

__global__ __launch_bounds__(256, 2) void lstm_gemm_fused(
    const unsigned short* __restrict__ A, const unsigned short* __restrict__ W,
    const float* __restrict__ bias, const float* __restrict__ c0,
    float* __restrict__ ht, float* __restrict__ ct)
{
    __shared__ char sm[65536];

    const int tid = threadIdx.x;
    const int l   = tid & 63;
    const int w   = tid >> 6;         // wave 0..3
    const int wm  = w >> 1;           // 0..1  (row half: 64 rows)
    const int wn  = w & 1;            // 0..1  (col half: 64 cols)

    // XCD-aware bijective swizzle (4096 blocks, %8==0; 512 contiguous per XCD)
    const int bid = blockIdx.x;
    const int nid = (bid & 7) * 512 + (bid >> 3);
    const int bm  = nid >> 5;         // 0..127 (M tiles of 128)
    const int bn  = nid & 31;         // 0..31  (N tiles of 128)

    f32x4 acc[4][4];
#pragma unroll
    for (int i = 0; i < 4; ++i)
#pragma unroll
        for (int j = 0; j < 4; ++j) acc[i][j] = (f32x4){0.f, 0.f, 0.f, 0.f};

    // ---- staging source addressing (inverse-swizzled), pointer-bumped per tile ----
    // wave w covers subtiles {w, w+4} of each 8-subtile kk-half chunk.
    const int srow = w * 16 + (l >> 2);                 // 0..63
    const int scb  = ((l & 3) << 4) ^ (l & 32);
    const char* Asrc = (const char*)A + (size_t)(bm * 128 + srow) * KB + scb;
    const char* Wsrc = (const char*)W + (size_t)(bn * 128 + srow) * KB + scb;
    const uint32_t wL = (uint32_t)w * 1024u;            // wave-uniform LDS dest part

#define STAGE_A(KK, BOFF) do { \
    gload16(Asrc + (KK) * 64,           sm + (BOFF) + (KK) * 8192u + wL); \
    gload16(Asrc + (KK) * 64 + 64 * KB, sm + (BOFF) + (KK) * 8192u + 4096u + wL); \
} while (0)
#define STAGE_B(KK, BOFF) do { \
    gload16(Wsrc + (KK) * 64,           sm + (BOFF) + 16384u + (KK) * 8192u + wL); \
    gload16(Wsrc + (KK) * 64 + 64 * KB, sm + (BOFF) + 16384u + (KK) * 8192u + 4096u + wL); \
} while (0)
#define BUMP do { Asrc += 128; Wsrc += 128; } while (0)

    // ---- fragment read addressing (swizzled, r5-verified formulas) ----
    const int rr = l & 15, kg = l >> 4;
    const uint32_t loff = (uint32_t)rr * 64u + (((uint32_t)kg * 16u) ^ (uint32_t)((rr & 8) << 2));
    const uint32_t Ard = (uint32_t)wm * 4096u + loff;             // + BOFF + KK*8192 + mf*1024
    const uint32_t Brd = 16384u + (uint32_t)wn * 4096u + loff;    // + BOFF + KK*8192 + nf*1024

    bf16x8 af[4], bf[4];

#define RD_PHASE(BOFF, KK) do { \
    _Pragma("unroll") \
    for (int i_ = 0; i_ < 4; ++i_) \
        af[i_] = *(const bf16x8*)(sm + (BOFF) + (KK) * 8192u + Ard + i_ * 1024u); \
    _Pragma("unroll") \
    for (int i_ = 0; i_ < 4; ++i_) \
        bf[i_] = *(const bf16x8*)(sm + (BOFF) + (KK) * 8192u + Brd + i_ * 1024u); \
} while (0)

#define MFMA16 do { \
    _Pragma("unroll") \
    for (int mf_ = 0; mf_ < 4; ++mf_) \
        _Pragma("unroll") \
        for (int nf_ = 0; nf_ < 4; ++nf_) \
            acc[mf_][nf_] = __builtin_amdgcn_mfma_f32_16x16x32_bf16( \
                af[mf_], bf[nf_], acc[mf_][nf_], 0, 0, 0); \
} while (0)

    // ---- prologue: stage tile0 fully (8 gloads); drain kk0 (kk1 stays in flight) ----
    STAGE_A(0, BUF0); STAGE_B(0, BUF0);
    STAGE_A(1, BUF0); STAGE_B(1, BUF0);
    BUMP;                                 // ptr -> t1
    asm volatile("s_waitcnt vmcnt(4)" ::: "memory");
    SCHED0; FENCE; BAR;

    // ---- main loop: 2 phases/tile (r2-verified discipline) ----
#define DO_TILE(CUR, NXT) do { \
    /* P0: kk0 */ \
    RD_PHASE(CUR, 0); \
    STAGE_A(0, NXT); STAGE_B(0, NXT); \
    PH_PRE; MFMA16; PH_POST_V; \
    /* P1: kk1 */ \
    RD_PHASE(CUR, 1); \
    STAGE_A(1, NXT); STAGE_B(1, NXT); \
    PH_PRE; MFMA16; PH_POST_V; \
    BUMP; \
} while (0)

#pragma unroll 1
    for (int tt = 0; tt < NT; tt += 2) {
        DO_TILE(BUF0, BUF1);
        DO_TILE(BUF1, BUF0);
    }
    // (final tile stages one-row-past-end garbage inside d_ws; never consumed --
    //  same pattern as r6-r12, all passed.)

    // ---- fused LSTM epilogue (r1/r5-verified shape) ----
    asm volatile("s_waitcnt vmcnt(0) lgkmcnt(0)" ::: "memory");
    FENCE; BAR;

    float* ep = (float*)(void*)sm + w * 1088;   // 16 rows x 68 floats per wave
    const int hbase = bn * 32 + wn * 16;
    const int rbase = bm * 128 + wm * 64;

#pragma unroll
    for (int mf = 0; mf < 4; ++mf) {
        // scatter acc slice (16 rows x 64 cols) to LDS, padded stride 68
#pragma unroll
        for (int nf = 0; nf < 4; ++nf)
#pragma unroll
            for (int r = 0; r < 4; ++r)
                ep[((l >> 4) * 4 + r) * 68 + nf * 16 + (l & 15)] = acc[mf][nf][r];

        // gather: lane -> (row, h); cols 4h..4h+3 = gates f,i,o,g
#pragma unroll
        for (int it = 0; it < 4; ++it) {
            const int row = (l >> 4) + it * 4;
            const int hs  = l & 15;
            f32x4 z = *(const f32x4*)(ep + row * 68 + hs * 4);
            const int hg = hbase + hs;
            const float4 bz = ((const float4*)bias)[hg];
            const int brow = rbase + mf * 16 + row;

            float zf = z.x + bz.x;
            float zi = z.y + bz.y;
            float zo = z.z + bz.z;
            float zg = z.w + bz.w;

            float fg = rcp1p(__expf(-zf));                   // sigmoid
            float ig = rcp1p(__expf(-zi));
            float og = rcp1p(__expf(-zo));
            float gg = 2.f * rcp1p(__expf(-2.f * zg)) - 1.f; // tanh

            int64_t oi = (int64_t)brow * H_DIM + hg;
            float c  = fg * c0[oi] + ig * gg;
            float hh = og * (2.f * rcp1p(__expf(-2.f * c)) - 1.f);
            ct[oi] = c;
            ht[oi] = hh;
        }
    }
}

extern "C" void kernel_launch(void* const* d_in, const int* in_sizes, int n_in,
                              void* d_out, int out_size, void* d_ws, size_t ws_size,
                              hipStream_t stream) {
    const float* x  = (const float*)d_in[0];
    const float* h0 = (const float*)d_in[1];
    const float* c0 = (const float*)d_in[2];
    const float* wi = (const float*)d_in[3];
    const float* bi = (const float*)d_in[4];
    const float* wh = (const float*)d_in[5];
    const float* bh = (const float*)d_in[6];

    float* ht = (float*)d_out;
    float* ct = ht + (int64_t)B_ROWS * H_DIM;

    char* ws = (char*)d_ws;
    unsigned short* A  = (unsigned short*)ws;                       // 64 MiB
    unsigned short* Wp = (unsigned short*)(ws + (64u << 20));       // 16 MiB
    float*          bs = (float*)(ws + (80u << 20));                // 16 KiB

    pack_a_kernel<<<32768, 256, 0, stream>>>(x, h0, A);
    pack_w_kernel<<<8192, 256, 0, stream>>>(wi, wh, bi, bh, Wp, bs);

    lstm_gemm_fused<<<4096, 256, 0, stream>>>(A, Wp, bs, c0, ht, ct);
}